// Round 5
// baseline (810.470 us; speedup 1.0000x reference)
//
#include <hip/hip_runtime.h>
#include <stdint.h>
#include <stddef.h>

#define Bsz 2
#define Ssz 4096
#define Csz 640
#define Hn 10
#define Dh 64
#define NSPLIT 4
#define QROWS 81920   // B*H*S = 20*4096

typedef __attribute__((ext_vector_type(8))) short bf16x8;
typedef __attribute__((ext_vector_type(4))) float f32x4;
typedef __attribute__((ext_vector_type(16))) float f32x16;

typedef __attribute__((address_space(1))) void as1_void;
typedef __attribute__((address_space(3))) void as3_void;

__device__ __forceinline__ void async16(const void* g, void* l) {
  __builtin_amdgcn_global_load_lds((as1_void*)(g), (as3_void*)(l), 16, 0, 0);
}

__device__ __forceinline__ ushort f2bf(float f) {
  union { float f; uint32_t u; } v; v.f = f;
  return (ushort)((v.u + 0x7FFFu + ((v.u >> 16) & 1u)) >> 16);
}

// pack two fp32 -> bf16x2 (truncation) in one v_perm_b32
__device__ __forceinline__ uint32_t pack_bf16(float lo, float hi) {
  return __builtin_amdgcn_perm(__float_as_uint(hi), __float_as_uint(lo), 0x07060302u);
}

__device__ __forceinline__ float bf_lo(uint32_t u) {
  return __uint_as_float(u << 16);
}
__device__ __forceinline__ float bf_hi(uint32_t u) {
  return __uint_as_float(u & 0xFFFF0000u);
}

// one-instruction exp2
__device__ __forceinline__ float fast_exp2(float x) {
#if __has_builtin(__builtin_amdgcn_exp2f)
  return __builtin_amdgcn_exp2f(x);
#else
  return __exp2f(x);
#endif
}

// scale folded into Q: 1/sqrt(64) * log2(e)
#define QSCALE 0.1803368801111204f

__global__ __launch_bounds__(256) void cvt_bf16(const float* __restrict__ in,
                                                ushort* __restrict__ out, int n4) {
  int i = blockIdx.x * 256 + threadIdx.x;
  if (i < n4) {
    const float4 v = ((const float4*)in)[i];
    ushort4 o;
    o.x = f2bf(v.x); o.y = f2bf(v.y); o.z = f2bf(v.z); o.w = f2bf(v.w);
    ((ushort4*)out)[i] = o;
  }
}

// fused 4-weight conversion (blockIdx.y picks the matrix); n4 = 102400 each
__global__ __launch_bounds__(256) void cvt4_bf16(
    const float* __restrict__ i0, const float* __restrict__ i1,
    const float* __restrict__ i2, const float* __restrict__ i3,
    ushort* __restrict__ o0, ushort* __restrict__ o1,
    ushort* __restrict__ o2, ushort* __restrict__ o3, int n4) {
  const float* in = (blockIdx.y == 0) ? i0 : (blockIdx.y == 1) ? i1
                    : (blockIdx.y == 2) ? i2 : i3;
  ushort* out = (blockIdx.y == 0) ? o0 : (blockIdx.y == 1) ? o1
                : (blockIdx.y == 2) ? o2 : o3;
  int i = blockIdx.x * 256 + threadIdx.x;
  if (i < n4) {
    const float4 v = ((const float4*)in)[i];
    ushort4 o;
    o.x = f2bf(v.x); o.y = f2bf(v.y); o.z = f2bf(v.z); o.w = f2bf(v.w);
    ((ushort4*)out)[i] = o;
  }
}

// C = A(bf16 [M,640]) * W^T(bf16 [N,640]); 128x128 tile, BK=64, 4 waves.
// MODE 0: QKV fused (blockIdx.y: 0-4 Q, 5-9 K, 10-14 V). Q/K -> [B,H,S,64] (Q pre-scaled
//         by QSCALE), V -> [B,H,64,S].
// MODE 1: out-proj + bias + residual -> fp32 [B,S,C].
template<int MODE>
__global__ __launch_bounds__(256) void gemm_k(
    const ushort* __restrict__ A, const ushort* __restrict__ W0,
    const ushort* __restrict__ W1, const ushort* __restrict__ W2,
    ushort* __restrict__ Qh, ushort* __restrict__ Kh, ushort* __restrict__ Vt,
    const float* __restrict__ bias, const float* __restrict__ residual,
    float* __restrict__ outf)
{
  __shared__ ushort As[128 * 64];
  __shared__ ushort Bs[128 * 64];
  const int t = threadIdx.x;
  const int lane = t & 63;
  const int w = t >> 6;
  const int quad = lane >> 4;
  const int l15 = lane & 15;
  const int m0 = blockIdx.x * 128;
  const int wub = t & ~63;

  int n0, mat;
  const ushort* W;
  if (MODE == 0) {
    mat = blockIdx.y / 5;
    n0 = (blockIdx.y % 5) * 128;
    W = (mat == 0) ? W0 : ((mat == 1) ? W1 : W2);
  } else {
    mat = 0;
    n0 = blockIdx.y * 128;
    W = W0;
  }
  const int qm = (w >> 1) * 64;
  const int qn = (w & 1) * 64;

  f32x4 acc[4][4];
  const f32x4 zero4 = {0.f, 0.f, 0.f, 0.f};
#pragma unroll
  for (int i = 0; i < 4; ++i)
#pragma unroll
    for (int j = 0; j < 4; ++j) acc[i][j] = zero4;

  for (int k0 = 0; k0 < Csz; k0 += 64) {
    __syncthreads();
#pragma unroll
    for (int s = 0; s < 4; ++s) {
      int L = s * 256 + t;
      int row = L >> 3, pc = L & 7;
      int c = pc ^ (row & 7);
      async16(A + (size_t)(m0 + row) * Csz + k0 + c * 8,
              (char*)As + (s * 256 + wub) * 16);
    }
#pragma unroll
    for (int s = 0; s < 4; ++s) {
      int L = s * 256 + t;
      int row = L >> 3, pc = L & 7;
      int c = pc ^ (row & 7);
      async16(W + (size_t)(n0 + row) * Csz + k0 + c * 8,
              (char*)Bs + (s * 256 + wub) * 16);
    }
    __syncthreads();
#pragma unroll
    for (int ks = 0; ks < 2; ++ks) {
      bf16x8 af[4], bfr[4];
#pragma unroll
      for (int i = 0; i < 4; ++i) {
        int row = qm + i * 16 + l15;
        int pc = (ks * 4 + quad) ^ (row & 7);
        af[i] = *(const bf16x8*)(As + row * 64 + pc * 8);
      }
#pragma unroll
      for (int j = 0; j < 4; ++j) {
        int row = qn + j * 16 + l15;
        int pc = (ks * 4 + quad) ^ (row & 7);
        bfr[j] = *(const bf16x8*)(Bs + row * 64 + pc * 8);
      }
#pragma unroll
      for (int i = 0; i < 4; ++i)
#pragma unroll
        for (int j = 0; j < 4; ++j)
          acc[i][j] = __builtin_amdgcn_mfma_f32_16x16x32_bf16(af[i], bfr[j], acc[i][j], 0, 0, 0);
    }
  }

  if (MODE == 0) {
    if (mat < 2) {
      ushort* __restrict__ dst = (mat == 0) ? Qh : Kh;
      const float sc = (mat == 0) ? QSCALE : 1.0f;
#pragma unroll
      for (int j = 0; j < 4; ++j) {
        int n = n0 + qn + j * 16 + l15;
        int h = n >> 6, dh = n & 63;
#pragma unroll
        for (int i = 0; i < 4; ++i) {
#pragma unroll
          for (int r = 0; r < 4; ++r) {
            int m = m0 + qm + i * 16 + quad * 4 + r;
            int b = m >> 12, sidx = m & 4095;
            dst[(((size_t)b * Hn + h) * Ssz + sidx) * Dh + dh] = f2bf(acc[i][j][r] * sc);
          }
        }
      }
    } else {
#pragma unroll
      for (int j = 0; j < 4; ++j) {
        int n = n0 + qn + j * 16 + l15;
        int h = n >> 6, dh = n & 63;
#pragma unroll
        for (int i = 0; i < 4; ++i) {
          int mb = m0 + qm + i * 16 + quad * 4;
          int b = mb >> 12, sidx = mb & 4095;
          ushort4 pk;
          pk.x = f2bf(acc[i][j][0]); pk.y = f2bf(acc[i][j][1]);
          pk.z = f2bf(acc[i][j][2]); pk.w = f2bf(acc[i][j][3]);
          *(ushort4*)(Vt + (((size_t)b * Hn + h) * Dh + dh) * Ssz + sidx) = pk;
        }
      }
    }
  } else {
#pragma unroll
    for (int j = 0; j < 4; ++j) {
      int n = n0 + qn + j * 16 + l15;
      float bs = bias[n];
#pragma unroll
      for (int i = 0; i < 4; ++i) {
#pragma unroll
        for (int r = 0; r < 4; ++r) {
          int m = m0 + qm + i * 16 + quad * 4 + r;
          size_t idx = (size_t)m * Csz + n;
          outf[idx] = acc[i][j][r] + bs + residual[idx];
        }
      }
    }
  }
}

// Flash attention v5: 4 waves x 64 q = 256 q per block; kv-split via blockIdx.z
// (each block sweeps 1024 kv = 16 tiles of 64). Shared double-buffered K/V LDS
// tiles (32 KB), raw s_barrier (no compiler vmcnt(0) drain) + manual vmcnt(4)
// so next-tile DMA stays in flight across barriers.
// S^T = K*Q^T (32x32x16), static-max exp2 softmax, P^T in regs via xor-32
// exchange, O^T = V^T*P^T; K/V frags each feed 2 MFMAs (q-halves).
// Outputs UNNORMALIZED O^T partials (bf16) + l partials (fp32); combine_k
// finishes. Qh/Kh: [BH,S,64] bf16; Vt: [BH,64,S] bf16.
__global__ __launch_bounds__(256, 4) void attn_k(
    const ushort* __restrict__ Qh, const ushort* __restrict__ Kh,
    const ushort* __restrict__ Vt, ushort* __restrict__ Opart,
    float* __restrict__ lpart)
{
  __shared__ ushort Ks[2][64 * 64];
  __shared__ ushort Vs[2][64 * 64];

  const int t = threadIdx.x;
  const int lane = t & 63;
  const int w = t >> 6;          // 0..3
  const int l31 = lane & 31;
  const int hi = lane >> 5;
  const int bh = blockIdx.y;     // 0..19
  const size_t qk_off = (size_t)bh * Ssz * Dh;
  const size_t v_off = (size_t)bh * Dh * Ssz;
  const int qbase = blockIdx.x * 256 + w * 64;
  const int kvbase = blockIdx.z * (Ssz / NSPLIT);

  // preload Q B-frags for both q-halves: B[k=d][n=q], frag ks covers
  // d = ks*16 + hi*8 + j
  bf16x8 qf[2][4];
#pragma unroll
  for (int qh = 0; qh < 2; ++qh) {
    int q = qbase + qh * 32 + l31;
#pragma unroll
    for (int ks = 0; ks < 4; ++ks)
      qf[qh][ks] = *(const bf16x8*)(Qh + qk_off + (size_t)q * Dh + ks * 16 + hi * 8);
  }

  f32x16 z16;
#pragma unroll
  for (int i = 0; i < 16; ++i) z16[i] = 0.f;

  f32x16 Oa[2][2];   // [qh][mt]
#pragma unroll
  for (int qh = 0; qh < 2; ++qh)
#pragma unroll
    for (int mt = 0; mt < 2; ++mt) Oa[qh][mt] = z16;
  float lp[2] = {0.f, 0.f};

  const int row8 = lane >> 3;    // staging row offset within 8-row group
  const int pcs = lane & 7;      // staging chunk slot
  // stage this wave's share (2 K-chunks + 2 V-chunks of 1KB) of tile (kv rel)
#define STAGE(bi, kv)                                                          \
  {                                                                            \
    _Pragma("unroll") for (int s = 0; s < 2; ++s) {                            \
      int i = w * 2 + s;                                                       \
      int row = i * 8 + row8;                                                  \
      int c = pcs ^ (row & 7);                                                 \
      async16(Kh + qk_off + (size_t)(kvbase + (kv) + row) * Dh + c * 8,        \
              (char*)&Ks[bi][0] + i * 1024);                                   \
    }                                                                          \
    _Pragma("unroll") for (int s = 0; s < 2; ++s) {                            \
      int i = w * 2 + s;                                                       \
      int row = i * 8 + row8;                                                  \
      int c = pcs ^ (row & 7);                                                 \
      async16(Vt + v_off + (size_t)row * Ssz + kvbase + (kv) + c * 8,          \
              (char*)&Vs[bi][0] + i * 1024);                                   \
    }                                                                          \
  }

  STAGE(0, 0);

  const int NIT = (Ssz / NSPLIT) / 64;  // 16
  for (int it = 0; it < NIT; ++it) {
    const int cb = it & 1;
    // WAR guard: all waves finished reading buf cb^1 (iter it-1)
    asm volatile("s_barrier" ::: "memory");
    if (it + 1 < NIT) {
      STAGE(cb ^ 1, (it + 1) * 64);
      asm volatile("s_waitcnt vmcnt(4)" ::: "memory");  // own cb chunks landed
    } else {
      asm volatile("s_waitcnt vmcnt(0)" ::: "memory");
    }
    // RAW guard: every wave's cb chunks landed
    asm volatile("s_barrier" ::: "memory");

    const ushort* __restrict__ Kc = &Ks[cb][0];
    const ushort* __restrict__ Vc = &Vs[cb][0];

    // S^T = K * Q^T, then exp -> packed P^T pairs, per tau half (kv rows)
    uint32_t pk[2][2][8];  // [qh][tau][a]
#pragma unroll
    for (int tau = 0; tau < 2; ++tau) {
      f32x16 Sq[2];
      int row = tau * 32 + l31;
#pragma unroll
      for (int ks = 0; ks < 4; ++ks) {
        int pc = (ks * 2 + hi) ^ (row & 7);
        bf16x8 kf = *(const bf16x8*)(Kc + row * 64 + pc * 8);
        Sq[0] = __builtin_amdgcn_mfma_f32_32x32x16_bf16(kf, qf[0][ks],
                                                        ks == 0 ? z16 : Sq[0], 0, 0, 0);
        Sq[1] = __builtin_amdgcn_mfma_f32_32x32x16_bf16(kf, qf[1][ks],
                                                        ks == 0 ? z16 : Sq[1], 0, 0, 0);
      }
#pragma unroll
      for (int qh = 0; qh < 2; ++qh) {
#pragma unroll
        for (int a = 0; a < 8; ++a) {
          float p0 = fast_exp2(Sq[qh][2 * a]);
          float p1 = fast_exp2(Sq[qh][2 * a + 1]);
          lp[qh] += p0 + p1;
          pk[qh][tau][a] = pack_bf16(p0, p1);
        }
      }
    }

    // O^T += V^T P^T. B-frag ks2 needs kv pairs g = ks2*8 + hi*4 + p
#pragma unroll
    for (int ks2 = 0; ks2 < 4; ++ks2) {
      const int ts = ks2 >> 1;
      const int bA = (2 * ks2) & 3;       // pair-group for hi=0
      const int bB = (2 * ks2 + 1) & 3;   // pair-group for hi=1
      bf16x8 pf[2];
#pragma unroll
      for (int qh = 0; qh < 2; ++qh) {
        uint32_t xA0 = pk[qh][ts][2 * bA], xA1 = pk[qh][ts][2 * bA + 1];
        uint32_t xB0 = pk[qh][ts][2 * bB], xB1 = pk[qh][ts][2 * bB + 1];
        uint32_t own0 = hi ? xB0 : xA0, own1 = hi ? xB1 : xA1;
        uint32_t snd0 = hi ? xA0 : xB0, snd1 = hi ? xA1 : xB1;
        uint32_t rcv0 = (uint32_t)__shfl_xor((int)snd0, 32, 64);
        uint32_t rcv1 = (uint32_t)__shfl_xor((int)snd1, 32, 64);
        union { uint32_t u[4]; bf16x8 v; } pu;
        pu.u[0] = hi ? rcv0 : own0;
        pu.u[1] = hi ? rcv1 : own1;
        pu.u[2] = hi ? own0 : rcv0;
        pu.u[3] = hi ? own1 : rcv1;
        pf[qh] = pu.v;
      }
#pragma unroll
      for (int mt = 0; mt < 2; ++mt) {
        int row = mt * 32 + l31;
        int pc = (ks2 * 2 + hi) ^ (row & 7);
        bf16x8 vf = *(const bf16x8*)(Vc + row * 64 + pc * 8);
        Oa[0][mt] = __builtin_amdgcn_mfma_f32_32x32x16_bf16(vf, pf[0], Oa[0][mt], 0, 0, 0);
        Oa[1][mt] = __builtin_amdgcn_mfma_f32_32x32x16_bf16(vf, pf[1], Oa[1][mt], 0, 0, 0);
      }
    }
  }
#undef STAGE

  // epilogue: write UNNORMALIZED partials. l = own half + xor-32 partner half.
  const size_t prow_base = (size_t)blockIdx.z * QROWS + (size_t)bh * Ssz;
#pragma unroll
  for (int qh = 0; qh < 2; ++qh) {
    float l_part = lp[qh];
    float l_tot = l_part + __shfl_xor(l_part, 32, 64);
    int q = qbase + qh * 32 + l31;
    if (hi == 0) lpart[prow_base + q] = l_tot;
    ushort* dst = Opart + (prow_base + q) * 64;
#pragma unroll
    for (int mt = 0; mt < 2; ++mt) {
#pragma unroll
      for (int g = 0; g < 4; ++g) {
        int dh0 = mt * 32 + 8 * g + 4 * hi;
        uint2 val;
        val.x = pack_bf16(Oa[qh][mt][4 * g + 0], Oa[qh][mt][4 * g + 1]);
        val.y = pack_bf16(Oa[qh][mt][4 * g + 2], Oa[qh][mt][4 * g + 3]);
        *(uint2*)(dst + dh0) = val;
      }
    }
  }
}

// sum NSPLIT partials, normalize by total l, scatter to attnb [B,S,C] bf16
__global__ __launch_bounds__(256) void combine_k(
    const ushort* __restrict__ Opart, const float* __restrict__ lpart,
    ushort* __restrict__ attnb)
{
  int gid = blockIdx.x * 256 + threadIdx.x;   // QROWS*16 total
  int row = gid >> 4;                         // 0..QROWS-1
  int dh0 = (gid & 15) * 4;
  int bh = row >> 12, q = row & 4095;
  int b = bh / Hn, h = bh % Hn;
  float a0 = 0.f, a1 = 0.f, a2 = 0.f, a3 = 0.f, lsum = 0.f;
#pragma unroll
  for (int sp = 0; sp < NSPLIT; ++sp) {
    uint2 v = *(const uint2*)(Opart + ((size_t)sp * QROWS + row) * 64 + dh0);
    a0 += bf_lo(v.x); a1 += bf_hi(v.x);
    a2 += bf_lo(v.y); a3 += bf_hi(v.y);
    lsum += lpart[(size_t)sp * QROWS + row];
  }
  float inv = 1.0f / lsum;
  uint2 o;
  o.x = pack_bf16(a0 * inv, a1 * inv);
  o.y = pack_bf16(a2 * inv, a3 * inv);
  *(uint2*)(attnb + ((size_t)b * Ssz + q) * Csz + h * Dh + dh0) = o;
}

extern "C" void kernel_launch(void* const* d_in, const int* in_sizes, int n_in,
                              void* d_out, int out_size, void* d_ws, size_t ws_size,
                              hipStream_t stream) {
  (void)in_sizes; (void)n_in; (void)out_size; (void)ws_size;
  const float* hs = (const float*)d_in[0];
  const float* Wq = (const float*)d_in[1];
  const float* Wk = (const float*)d_in[2];
  const float* Wv = (const float*)d_in[3];
  const float* Wo = (const float*)d_in[4];
  const float* bo = (const float*)d_in[5];
  float* out = (float*)d_out;

  char* ws = (char*)d_ws;
  ushort* Xbf = (ushort*)(ws);                               // 10485760 B
  ushort* Wqb = (ushort*)(ws + 10485760);                    // 819200 B each
  ushort* Wkb = (ushort*)(ws + 10485760 + 819200);
  ushort* Wvb = (ushort*)(ws + 10485760 + 2 * 819200);
  ushort* Wob = (ushort*)(ws + 10485760 + 3 * 819200);
  ushort* Qh  = (ushort*)(ws + 13762560);                    // [20,4096,64]
  ushort* Kh  = (ushort*)(ws + 13762560 + 10485760);
  ushort* Vt  = (ushort*)(ws + 13762560 + 2 * 10485760);     // [20,64,4096]
  ushort* attnb = (ushort*)(ws + 13762560 + 3 * 10485760);   // [8192,640]
  ushort* Opart = (ushort*)(ws + 55705600);                  // [4][81920][64] bf16 = 41.9MB
  float*  lpart = (float*)(ws + 55705600 + 41943040);        // [4][81920] f32

  hipLaunchKernelGGL(cvt_bf16, dim3(5120), dim3(256), 0, stream, hs, Xbf, 1310720);
  hipLaunchKernelGGL(cvt4_bf16, dim3(400, 4), dim3(256), 0, stream,
                     Wq, Wk, Wv, Wo, Wqb, Wkb, Wvb, Wob, 102400);

  hipLaunchKernelGGL((gemm_k<0>), dim3(64, 15), dim3(256), 0, stream,
                     Xbf, Wqb, Wkb, Wvb, Qh, Kh, Vt, (const float*)nullptr,
                     (const float*)nullptr, (float*)nullptr);
  hipLaunchKernelGGL(attn_k, dim3(16, 20, NSPLIT), dim3(256), 0, stream,
                     Qh, Kh, Vt, Opart, lpart);
  hipLaunchKernelGGL(combine_k, dim3(QROWS / 16), dim3(256), 0, stream,
                     Opart, lpart, attnb);
  hipLaunchKernelGGL((gemm_k<1>), dim3(64, 5), dim3(256), 0, stream,
                     attnb, Wob, (const ushort*)nullptr, (const ushort*)nullptr,
                     (ushort*)nullptr, (ushort*)nullptr, (ushort*)nullptr,
                     bo, hs, out);
}

// Round 6
// 253.162 us; speedup vs baseline: 3.2014x; 3.2014x over previous
//
#include <hip/hip_runtime.h>
#include <stdint.h>
#include <stddef.h>

#define Bsz 2
#define Ssz 4096
#define Csz 640
#define Hn 10
#define Dh 64
#define NSPLIT 4
#define QROWS 81920   // B*H*S = 20*4096

typedef __attribute__((ext_vector_type(8))) short bf16x8;
typedef __attribute__((ext_vector_type(4))) float f32x4;
typedef __attribute__((ext_vector_type(16))) float f32x16;

typedef __attribute__((address_space(1))) void as1_void;
typedef __attribute__((address_space(3))) void as3_void;

__device__ __forceinline__ void async16(const void* g, void* l) {
  __builtin_amdgcn_global_load_lds((as1_void*)(g), (as3_void*)(l), 16, 0, 0);
}

__device__ __forceinline__ ushort f2bf(float f) {
  union { float f; uint32_t u; } v; v.f = f;
  return (ushort)((v.u + 0x7FFFu + ((v.u >> 16) & 1u)) >> 16);
}

// pack two fp32 -> bf16x2 (truncation) in one v_perm_b32
__device__ __forceinline__ uint32_t pack_bf16(float lo, float hi) {
  return __builtin_amdgcn_perm(__float_as_uint(hi), __float_as_uint(lo), 0x07060302u);
}

__device__ __forceinline__ float bf_lo(uint32_t u) {
  return __uint_as_float(u << 16);
}
__device__ __forceinline__ float bf_hi(uint32_t u) {
  return __uint_as_float(u & 0xFFFF0000u);
}

// one-instruction exp2
__device__ __forceinline__ float fast_exp2(float x) {
#if __has_builtin(__builtin_amdgcn_exp2f)
  return __builtin_amdgcn_exp2f(x);
#else
  return __exp2f(x);
#endif
}

// scale folded into Q: 1/sqrt(64) * log2(e)
#define QSCALE 0.1803368801111204f

__global__ __launch_bounds__(256) void cvt_bf16(const float* __restrict__ in,
                                                ushort* __restrict__ out, int n4) {
  int i = blockIdx.x * 256 + threadIdx.x;
  if (i < n4) {
    const float4 v = ((const float4*)in)[i];
    ushort4 o;
    o.x = f2bf(v.x); o.y = f2bf(v.y); o.z = f2bf(v.z); o.w = f2bf(v.w);
    ((ushort4*)out)[i] = o;
  }
}

// fused 4-weight conversion (blockIdx.y picks the matrix); n4 = 102400 each
__global__ __launch_bounds__(256) void cvt4_bf16(
    const float* __restrict__ i0, const float* __restrict__ i1,
    const float* __restrict__ i2, const float* __restrict__ i3,
    ushort* __restrict__ o0, ushort* __restrict__ o1,
    ushort* __restrict__ o2, ushort* __restrict__ o3, int n4) {
  const float* in = (blockIdx.y == 0) ? i0 : (blockIdx.y == 1) ? i1
                    : (blockIdx.y == 2) ? i2 : i3;
  ushort* out = (blockIdx.y == 0) ? o0 : (blockIdx.y == 1) ? o1
                : (blockIdx.y == 2) ? o2 : o3;
  int i = blockIdx.x * 256 + threadIdx.x;
  if (i < n4) {
    const float4 v = ((const float4*)in)[i];
    ushort4 o;
    o.x = f2bf(v.x); o.y = f2bf(v.y); o.z = f2bf(v.z); o.w = f2bf(v.w);
    ((ushort4*)out)[i] = o;
  }
}

// C = A(bf16 [M,640]) * W^T(bf16 [N,640]); 128x128 tile, BK=64, 4 waves.
// MODE 0: QKV fused (blockIdx.y: 0-4 Q, 5-9 K, 10-14 V). Q/K -> [B,H,S,64] (Q pre-scaled
//         by QSCALE), V -> [B,H,64,S].
// MODE 1: out-proj + bias + residual -> fp32 [B,S,C].
template<int MODE>
__global__ __launch_bounds__(256) void gemm_k(
    const ushort* __restrict__ A, const ushort* __restrict__ W0,
    const ushort* __restrict__ W1, const ushort* __restrict__ W2,
    ushort* __restrict__ Qh, ushort* __restrict__ Kh, ushort* __restrict__ Vt,
    const float* __restrict__ bias, const float* __restrict__ residual,
    float* __restrict__ outf)
{
  __shared__ ushort As[128 * 64];
  __shared__ ushort Bs[128 * 64];
  const int t = threadIdx.x;
  const int lane = t & 63;
  const int w = t >> 6;
  const int quad = lane >> 4;
  const int l15 = lane & 15;
  const int m0 = blockIdx.x * 128;
  const int wub = t & ~63;

  int n0, mat;
  const ushort* W;
  if (MODE == 0) {
    mat = blockIdx.y / 5;
    n0 = (blockIdx.y % 5) * 128;
    W = (mat == 0) ? W0 : ((mat == 1) ? W1 : W2);
  } else {
    mat = 0;
    n0 = blockIdx.y * 128;
    W = W0;
  }
  const int qm = (w >> 1) * 64;
  const int qn = (w & 1) * 64;

  f32x4 acc[4][4];
  const f32x4 zero4 = {0.f, 0.f, 0.f, 0.f};
#pragma unroll
  for (int i = 0; i < 4; ++i)
#pragma unroll
    for (int j = 0; j < 4; ++j) acc[i][j] = zero4;

  for (int k0 = 0; k0 < Csz; k0 += 64) {
    __syncthreads();
#pragma unroll
    for (int s = 0; s < 4; ++s) {
      int L = s * 256 + t;
      int row = L >> 3, pc = L & 7;
      int c = pc ^ (row & 7);
      async16(A + (size_t)(m0 + row) * Csz + k0 + c * 8,
              (char*)As + (s * 256 + wub) * 16);
    }
#pragma unroll
    for (int s = 0; s < 4; ++s) {
      int L = s * 256 + t;
      int row = L >> 3, pc = L & 7;
      int c = pc ^ (row & 7);
      async16(W + (size_t)(n0 + row) * Csz + k0 + c * 8,
              (char*)Bs + (s * 256 + wub) * 16);
    }
    __syncthreads();
#pragma unroll
    for (int ks = 0; ks < 2; ++ks) {
      bf16x8 af[4], bfr[4];
#pragma unroll
      for (int i = 0; i < 4; ++i) {
        int row = qm + i * 16 + l15;
        int pc = (ks * 4 + quad) ^ (row & 7);
        af[i] = *(const bf16x8*)(As + row * 64 + pc * 8);
      }
#pragma unroll
      for (int j = 0; j < 4; ++j) {
        int row = qn + j * 16 + l15;
        int pc = (ks * 4 + quad) ^ (row & 7);
        bfr[j] = *(const bf16x8*)(Bs + row * 64 + pc * 8);
      }
#pragma unroll
      for (int i = 0; i < 4; ++i)
#pragma unroll
        for (int j = 0; j < 4; ++j)
          acc[i][j] = __builtin_amdgcn_mfma_f32_16x16x32_bf16(af[i], bfr[j], acc[i][j], 0, 0, 0);
    }
  }

  if (MODE == 0) {
    if (mat < 2) {
      ushort* __restrict__ dst = (mat == 0) ? Qh : Kh;
      const float sc = (mat == 0) ? QSCALE : 1.0f;
#pragma unroll
      for (int j = 0; j < 4; ++j) {
        int n = n0 + qn + j * 16 + l15;
        int h = n >> 6, dh = n & 63;
#pragma unroll
        for (int i = 0; i < 4; ++i) {
#pragma unroll
          for (int r = 0; r < 4; ++r) {
            int m = m0 + qm + i * 16 + quad * 4 + r;
            int b = m >> 12, sidx = m & 4095;
            dst[(((size_t)b * Hn + h) * Ssz + sidx) * Dh + dh] = f2bf(acc[i][j][r] * sc);
          }
        }
      }
    } else {
#pragma unroll
      for (int j = 0; j < 4; ++j) {
        int n = n0 + qn + j * 16 + l15;
        int h = n >> 6, dh = n & 63;
#pragma unroll
        for (int i = 0; i < 4; ++i) {
          int mb = m0 + qm + i * 16 + quad * 4;
          int b = mb >> 12, sidx = mb & 4095;
          ushort4 pk;
          pk.x = f2bf(acc[i][j][0]); pk.y = f2bf(acc[i][j][1]);
          pk.z = f2bf(acc[i][j][2]); pk.w = f2bf(acc[i][j][3]);
          *(ushort4*)(Vt + (((size_t)b * Hn + h) * Dh + dh) * Ssz + sidx) = pk;
        }
      }
    }
  } else {
#pragma unroll
    for (int j = 0; j < 4; ++j) {
      int n = n0 + qn + j * 16 + l15;
      float bs = bias[n];
#pragma unroll
      for (int i = 0; i < 4; ++i) {
#pragma unroll
        for (int r = 0; r < 4; ++r) {
          int m = m0 + qm + i * 16 + quad * 4 + r;
          size_t idx = (size_t)m * Csz + n;
          outf[idx] = acc[i][j][r] + bs + residual[idx];
        }
      }
    }
  }
}

// Flash attention v6: r5 structure with the VGPR cap fixed.
// 4 waves x 64 q = 256 q per block; kv-split via blockIdx.z (each block sweeps
// 1024 kv = 16 tiles of 64). Shared double-buffered K/V LDS tiles (32 KB), raw
// s_barrier (no compiler vmcnt(0) drain) + manual vmcnt(4) so next-tile DMA
// stays in flight across barriers.
// S^T = K*Q^T (32x32x16), static-max exp2 softmax, P^T in regs via xor-32
// exchange, O^T = V^T*P^T; K/V frags each feed 2 MFMAs (q-halves).
// Outputs UNNORMALIZED O^T partials (bf16) + l partials (fp32); combine_k
// finishes. Qh/Kh: [BH,S,64] bf16; Vt: [BH,64,S] bf16.
// launch_bounds(256,2): cap 256 VGPR — r5's (256,4) forced a 64-VGPR budget
// and spilled 3 GB/dispatch to scratch. ~120 VGPR -> 4 waves/SIMD naturally.
__global__ __launch_bounds__(256, 2) void attn_k(
    const ushort* __restrict__ Qh, const ushort* __restrict__ Kh,
    const ushort* __restrict__ Vt, ushort* __restrict__ Opart,
    float* __restrict__ lpart)
{
  __shared__ ushort Ks[2][64 * 64];
  __shared__ ushort Vs[2][64 * 64];

  const int t = threadIdx.x;
  const int lane = t & 63;
  const int w = t >> 6;          // 0..3
  const int l31 = lane & 31;
  const int hi = lane >> 5;
  const int bh = blockIdx.y;     // 0..19
  const size_t qk_off = (size_t)bh * Ssz * Dh;
  const size_t v_off = (size_t)bh * Dh * Ssz;
  const int qbase = blockIdx.x * 256 + w * 64;
  const int kvbase = blockIdx.z * (Ssz / NSPLIT);

  // preload Q B-frags for both q-halves: B[k=d][n=q], frag ks covers
  // d = ks*16 + hi*8 + j
  bf16x8 qf[2][4];
#pragma unroll
  for (int qh = 0; qh < 2; ++qh) {
    int q = qbase + qh * 32 + l31;
#pragma unroll
    for (int ks = 0; ks < 4; ++ks)
      qf[qh][ks] = *(const bf16x8*)(Qh + qk_off + (size_t)q * Dh + ks * 16 + hi * 8);
  }

  f32x16 z16;
#pragma unroll
  for (int i = 0; i < 16; ++i) z16[i] = 0.f;

  f32x16 Oa[2][2];   // [qh][mt]
#pragma unroll
  for (int qh = 0; qh < 2; ++qh)
#pragma unroll
    for (int mt = 0; mt < 2; ++mt) Oa[qh][mt] = z16;
  float lp[2] = {0.f, 0.f};

  const int row8 = lane >> 3;    // staging row offset within 8-row group
  const int pcs = lane & 7;      // staging chunk slot
  // stage this wave's share (2 K-chunks + 2 V-chunks of 1KB) of tile (kv rel)
#define STAGE(bi, kv)                                                          \
  {                                                                            \
    _Pragma("unroll") for (int s = 0; s < 2; ++s) {                            \
      int i = w * 2 + s;                                                       \
      int row = i * 8 + row8;                                                  \
      int c = pcs ^ (row & 7);                                                 \
      async16(Kh + qk_off + (size_t)(kvbase + (kv) + row) * Dh + c * 8,        \
              (char*)&Ks[bi][0] + i * 1024);                                   \
    }                                                                          \
    _Pragma("unroll") for (int s = 0; s < 2; ++s) {                            \
      int i = w * 2 + s;                                                       \
      int row = i * 8 + row8;                                                  \
      int c = pcs ^ (row & 7);                                                 \
      async16(Vt + v_off + (size_t)row * Ssz + kvbase + (kv) + c * 8,          \
              (char*)&Vs[bi][0] + i * 1024);                                   \
    }                                                                          \
  }

  STAGE(0, 0);

  const int NIT = (Ssz / NSPLIT) / 64;  // 16
  for (int it = 0; it < NIT; ++it) {
    const int cb = it & 1;
    // WAR guard: all waves finished reading buf cb^1 (iter it-1)
    asm volatile("s_barrier" ::: "memory");
    if (it + 1 < NIT) {
      STAGE(cb ^ 1, (it + 1) * 64);
      asm volatile("s_waitcnt vmcnt(4)" ::: "memory");  // own cb chunks landed
    } else {
      asm volatile("s_waitcnt vmcnt(0)" ::: "memory");
    }
    // RAW guard: every wave's cb chunks landed
    asm volatile("s_barrier" ::: "memory");

    const ushort* __restrict__ Kc = &Ks[cb][0];
    const ushort* __restrict__ Vc = &Vs[cb][0];

    // S^T = K * Q^T, then exp -> packed P^T pairs, per tau half (kv rows)
    uint32_t pk[2][2][8];  // [qh][tau][a]
#pragma unroll
    for (int tau = 0; tau < 2; ++tau) {
      f32x16 Sq[2];
      int row = tau * 32 + l31;
#pragma unroll
      for (int ks = 0; ks < 4; ++ks) {
        int pc = (ks * 2 + hi) ^ (row & 7);
        bf16x8 kf = *(const bf16x8*)(Kc + row * 64 + pc * 8);
        Sq[0] = __builtin_amdgcn_mfma_f32_32x32x16_bf16(kf, qf[0][ks],
                                                        ks == 0 ? z16 : Sq[0], 0, 0, 0);
        Sq[1] = __builtin_amdgcn_mfma_f32_32x32x16_bf16(kf, qf[1][ks],
                                                        ks == 0 ? z16 : Sq[1], 0, 0, 0);
      }
#pragma unroll
      for (int qh = 0; qh < 2; ++qh) {
#pragma unroll
        for (int a = 0; a < 8; ++a) {
          float p0 = fast_exp2(Sq[qh][2 * a]);
          float p1 = fast_exp2(Sq[qh][2 * a + 1]);
          lp[qh] += p0 + p1;
          pk[qh][tau][a] = pack_bf16(p0, p1);
        }
      }
    }

    // O^T += V^T P^T. B-frag ks2 needs kv pairs g = ks2*8 + hi*4 + p
#pragma unroll
    for (int ks2 = 0; ks2 < 4; ++ks2) {
      const int ts = ks2 >> 1;
      const int bA = (2 * ks2) & 3;       // pair-group for hi=0
      const int bB = (2 * ks2 + 1) & 3;   // pair-group for hi=1
      bf16x8 pf[2];
#pragma unroll
      for (int qh = 0; qh < 2; ++qh) {
        uint32_t xA0 = pk[qh][ts][2 * bA], xA1 = pk[qh][ts][2 * bA + 1];
        uint32_t xB0 = pk[qh][ts][2 * bB], xB1 = pk[qh][ts][2 * bB + 1];
        uint32_t own0 = hi ? xB0 : xA0, own1 = hi ? xB1 : xA1;
        uint32_t snd0 = hi ? xA0 : xB0, snd1 = hi ? xA1 : xB1;
        uint32_t rcv0 = (uint32_t)__shfl_xor((int)snd0, 32, 64);
        uint32_t rcv1 = (uint32_t)__shfl_xor((int)snd1, 32, 64);
        union { uint32_t u[4]; bf16x8 v; } pu;
        pu.u[0] = hi ? rcv0 : own0;
        pu.u[1] = hi ? rcv1 : own1;
        pu.u[2] = hi ? own0 : rcv0;
        pu.u[3] = hi ? own1 : rcv1;
        pf[qh] = pu.v;
      }
#pragma unroll
      for (int mt = 0; mt < 2; ++mt) {
        int row = mt * 32 + l31;
        int pc = (ks2 * 2 + hi) ^ (row & 7);
        bf16x8 vf = *(const bf16x8*)(Vc + row * 64 + pc * 8);
        Oa[0][mt] = __builtin_amdgcn_mfma_f32_32x32x16_bf16(vf, pf[0], Oa[0][mt], 0, 0, 0);
        Oa[1][mt] = __builtin_amdgcn_mfma_f32_32x32x16_bf16(vf, pf[1], Oa[1][mt], 0, 0, 0);
      }
    }
  }
#undef STAGE

  // epilogue: write UNNORMALIZED partials. l = own half + xor-32 partner half.
  const size_t prow_base = (size_t)blockIdx.z * QROWS + (size_t)bh * Ssz;
#pragma unroll
  for (int qh = 0; qh < 2; ++qh) {
    float l_part = lp[qh];
    float l_tot = l_part + __shfl_xor(l_part, 32, 64);
    int q = qbase + qh * 32 + l31;
    if (hi == 0) lpart[prow_base + q] = l_tot;
    ushort* dst = Opart + (prow_base + q) * 64;
#pragma unroll
    for (int mt = 0; mt < 2; ++mt) {
#pragma unroll
      for (int g = 0; g < 4; ++g) {
        int dh0 = mt * 32 + 8 * g + 4 * hi;
        uint2 val;
        val.x = pack_bf16(Oa[qh][mt][4 * g + 0], Oa[qh][mt][4 * g + 1]);
        val.y = pack_bf16(Oa[qh][mt][4 * g + 2], Oa[qh][mt][4 * g + 3]);
        *(uint2*)(dst + dh0) = val;
      }
    }
  }
}

// sum NSPLIT partials, normalize by total l, scatter to attnb [B,S,C] bf16
__global__ __launch_bounds__(256) void combine_k(
    const ushort* __restrict__ Opart, const float* __restrict__ lpart,
    ushort* __restrict__ attnb)
{
  int gid = blockIdx.x * 256 + threadIdx.x;   // QROWS*16 total
  int row = gid >> 4;                         // 0..QROWS-1
  int dh0 = (gid & 15) * 4;
  int bh = row >> 12, q = row & 4095;
  int b = bh / Hn, h = bh % Hn;
  float a0 = 0.f, a1 = 0.f, a2 = 0.f, a3 = 0.f, lsum = 0.f;
#pragma unroll
  for (int sp = 0; sp < NSPLIT; ++sp) {
    uint2 v = *(const uint2*)(Opart + ((size_t)sp * QROWS + row) * 64 + dh0);
    a0 += bf_lo(v.x); a1 += bf_hi(v.x);
    a2 += bf_lo(v.y); a3 += bf_hi(v.y);
    lsum += lpart[(size_t)sp * QROWS + row];
  }
  float inv = 1.0f / lsum;
  uint2 o;
  o.x = pack_bf16(a0 * inv, a1 * inv);
  o.y = pack_bf16(a2 * inv, a3 * inv);
  *(uint2*)(attnb + ((size_t)b * Ssz + q) * Csz + h * Dh + dh0) = o;
}

extern "C" void kernel_launch(void* const* d_in, const int* in_sizes, int n_in,
                              void* d_out, int out_size, void* d_ws, size_t ws_size,
                              hipStream_t stream) {
  (void)in_sizes; (void)n_in; (void)out_size; (void)ws_size;
  const float* hs = (const float*)d_in[0];
  const float* Wq = (const float*)d_in[1];
  const float* Wk = (const float*)d_in[2];
  const float* Wv = (const float*)d_in[3];
  const float* Wo = (const float*)d_in[4];
  const float* bo = (const float*)d_in[5];
  float* out = (float*)d_out;

  char* ws = (char*)d_ws;
  ushort* Xbf = (ushort*)(ws);                               // 10485760 B
  ushort* Wqb = (ushort*)(ws + 10485760);                    // 819200 B each
  ushort* Wkb = (ushort*)(ws + 10485760 + 819200);
  ushort* Wvb = (ushort*)(ws + 10485760 + 2 * 819200);
  ushort* Wob = (ushort*)(ws + 10485760 + 3 * 819200);
  ushort* Qh  = (ushort*)(ws + 13762560);                    // [20,4096,64]
  ushort* Kh  = (ushort*)(ws + 13762560 + 10485760);
  ushort* Vt  = (ushort*)(ws + 13762560 + 2 * 10485760);     // [20,64,4096]
  ushort* attnb = (ushort*)(ws + 13762560 + 3 * 10485760);   // [8192,640]
  ushort* Opart = (ushort*)(ws + 55705600);                  // [4][81920][64] bf16 = 41.9MB
  float*  lpart = (float*)(ws + 55705600 + 41943040);        // [4][81920] f32

  hipLaunchKernelGGL(cvt_bf16, dim3(5120), dim3(256), 0, stream, hs, Xbf, 1310720);
  hipLaunchKernelGGL(cvt4_bf16, dim3(400, 4), dim3(256), 0, stream,
                     Wq, Wk, Wv, Wo, Wqb, Wkb, Wvb, Wob, 102400);

  hipLaunchKernelGGL((gemm_k<0>), dim3(64, 15), dim3(256), 0, stream,
                     Xbf, Wqb, Wkb, Wvb, Qh, Kh, Vt, (const float*)nullptr,
                     (const float*)nullptr, (float*)nullptr);
  hipLaunchKernelGGL(attn_k, dim3(16, 20, NSPLIT), dim3(256), 0, stream,
                     Qh, Kh, Vt, Opart, lpart);
  hipLaunchKernelGGL(combine_k, dim3(QROWS / 16), dim3(256), 0, stream,
                     Opart, lpart, attnb);
  hipLaunchKernelGGL((gemm_k<1>), dim3(64, 5), dim3(256), 0, stream,
                     attnb, Wob, (const ushort*)nullptr, (const ushort*)nullptr,
                     (ushort*)nullptr, (ushort*)nullptr, (ushort*)nullptr,
                     bo, hs, out);
}